// Round 11
// baseline (356.752 us; speedup 1.0000x reference)
//
#include <hip/hip_runtime.h>
#include <hip/hip_bf16.h>

#define NH    16
#define NKVH  4
#define HD    128
#define WIN   1024
#define SEQ   2048
#define NB    4
#define QROW  (NH * HD)    // 2048 floats per token row (q, o)
#define KROW  (NKVH * HD)  // 512 elems per token row (k, v)
#define LOG2E 1.4426950408889634f
#define QSC   (0.08838834764831845f * LOG2E)
#define DTHR  8.0f         // defer-max threshold (log2 domain): P bounded by 2^8

#define KSTR 136   // Klds row stride in shorts (17x16B, 2-way max on A-frag reads)
#define VSTR 40    // Vlds row stride in shorts (5x16B)

typedef __attribute__((ext_vector_type(8))) short short8;
typedef __attribute__((ext_vector_type(4))) float float4v;

__device__ __forceinline__ unsigned short f2bf(float f) {
    unsigned int u = __float_as_uint(f);
    unsigned int r = (u + 0x7FFFu + ((u >> 16) & 1u)) >> 16;
    return (unsigned short)r;
}

__device__ __forceinline__ unsigned int pk2bf(float a, float b) {
    float2 t; t.x = a; t.y = b;
    __hip_bfloat162 h = __float22bfloat162_rn(t);
    union { __hip_bfloat162 h; unsigned int u; } cv;
    cv.h = h;
    return cv.u;
}

// ---- pre-pass 1: K fp32 -> bf16, layout preserved [token][kvh*128+d] ----
__global__ __launch_bounds__(256)
void cvt_k_kernel(const float* __restrict__ kg, unsigned short* __restrict__ kb) {
    const size_t idx = ((size_t)blockIdx.x * 256 + threadIdx.x) * 8;
    float4 a = *(const float4*)(kg + idx);
    float4 b = *(const float4*)(kg + idx + 4);
    uint4 w;
    w.x = pk2bf(a.x, a.y); w.y = pk2bf(a.z, a.w);
    w.z = pk2bf(b.x, b.y); w.w = pk2bf(b.z, b.w);
    *(uint4*)(kb + idx) = w;
}

// ---- pre-pass 2: V fp32 [token][kvh*128+d] -> V^T bf16 [b][kvh][d][seq] ----
#define VTSTR 72
__global__ __launch_bounds__(256)
void cvt_vt_kernel(const float* __restrict__ vg, unsigned short* __restrict__ vt) {
    __shared__ unsigned short T[128 * VTSTR];
    const int blk = blockIdx.x;          // 512 = b(4) x kvh(4) x kb(32)
    const int b   = blk >> 7;
    const int kvh = (blk >> 5) & 3;
    const int kb  = blk & 31;
    const int t   = threadIdx.x;

    // read: 64 keys x 128 dims fp32, coalesced; scatter-transpose into LDS
    const int klocal = t >> 2;
    const int d0     = (t & 3) * 32;
    const float* src = vg + (size_t)(b * SEQ + kb * 64 + klocal) * KROW + kvh * HD + d0;
#pragma unroll
    for (int c = 0; c < 8; ++c) {
        float4 x = *(const float4*)(src + c * 4);
        T[(d0 + c * 4 + 0) * VTSTR + klocal] = f2bf(x.x);
        T[(d0 + c * 4 + 1) * VTSTR + klocal] = f2bf(x.y);
        T[(d0 + c * 4 + 2) * VTSTR + klocal] = f2bf(x.z);
        T[(d0 + c * 4 + 3) * VTSTR + klocal] = f2bf(x.w);
    }
    __syncthreads();

    // write: dim-major rows, 64B per thread contiguous
    const int d    = t >> 1;
    const int half = t & 1;
    const unsigned short* s = &T[d * VTSTR + half * 32];
    unsigned short* dst = vt + ((size_t)((b * NKVH + kvh) * HD) + d) * SEQ + kb * 64 + half * 32;
#pragma unroll
    for (int c = 0; c < 4; ++c)
        *(uint4*)(dst + c * 8) = *(const uint4*)(s + c * 8);
}

// block = 256 threads = 4 waves; wave w = head kvh*4+w, 32 queries (qs=0..1).
// Round-6 verified structure: double-buffered LDS, ONE barrier per tile,
// prefetch issued after the barrier (in flight across the compute phase),
// defer-max, per-lane partial l_i (sink added once in epilogue), (256,3)
// (caps below ~170 VGPR spill catastrophically - rounds 4/7).
// Round-11 deltas (scheduling only, no inline asm - rounds 9/10 container
// failures correlate with the raw-asm variant):
//  - V fragments hoisted before softmax (lgkm latency hides under VALU)
//  - per-qs softmax->PV interleave (MFMA pipe busy during the other qs' VALU)
__global__ __launch_bounds__(256, 3)
void attn_swa_sink_kernel(const float* __restrict__ qg,
                          const unsigned short* __restrict__ kb,
                          const unsigned short* __restrict__ vt,
                          const float* __restrict__ sinks,
                          float* __restrict__ og) {
    __shared__ __align__(16) unsigned short Klds[2][32 * KSTR];   // [buf][interleaved key][dim]
    __shared__ __align__(16) unsigned short Vlds[2][128 * VSTR];  // [buf][dim][key] (V^T)

    // XCD swizzle: q-tiles of one (b,kvh) stay on one XCD; longest tiles first.
    const int gid  = blockIdx.x;          // 1024 = 8 xcd x 2 gsel x 64 qt
    const int xcd  = gid & 7;
    const int rest = gid >> 3;
    const int qt   = 63 - (rest >> 1);
    const int g    = ((rest & 1) << 3) | xcd;
    const int b    = g >> 2;
    const int kvh  = g & 3;

    const int tid  = threadIdx.x;
    const int wave = tid >> 6;
    const int lane = tid & 63;
    const int l15  = lane & 15;
    const int quad = lane >> 4;
    const int h    = kvh * 4 + wave;
    const int q0   = qt * 32;

    const float* qbase = qg + (size_t)(b * SEQ) * QROW;
    const unsigned short* kbase = kb + (size_t)(b * SEQ) * KROW + kvh * HD;
    const unsigned short* vtbase = vt + (size_t)((b * NKVH + kvh) * HD) * SEQ;

    // ---- Q fragments (B-operand of K*Q^T): col=query=l15, k=dim=quad*8+j (+32c) ----
    short8 qf[2][4];
#pragma unroll
    for (int qs = 0; qs < 2; ++qs) {
        const float* qr = qbase + (size_t)(q0 + qs * 16 + l15) * QROW + h * HD + quad * 8;
#pragma unroll
        for (int c = 0; c < 4; ++c) {
            float4 x = *(const float4*)(qr + c * 32);
            float4 y = *(const float4*)(qr + c * 32 + 4);
            union { unsigned int u[4]; short8 s; } cv;
            cv.u[0] = pk2bf(x.x * QSC, x.y * QSC);
            cv.u[1] = pk2bf(x.z * QSC, x.w * QSC);
            cv.u[2] = pk2bf(y.x * QSC, y.y * QSC);
            cv.u[3] = pk2bf(y.z * QSC, y.w * QSC);
            qf[qs][c] = cv.s;
        }
    }

    const float sinkv = sinks[h] * LOG2E;
    float m_i[2] = { sinkv, sinkv };
    float l_i[2] = { 0.0f, 0.0f };   // per-lane partial; sink added in epilogue
    float4v accO[2][8];   // row=query=quad*4+r, col=dim=f*16+l15
#pragma unroll
    for (int qs = 0; qs < 2; ++qs)
#pragma unroll
        for (int f = 0; f < 8; ++f) accO[qs][f] = (float4v)0.0f;

    // staging thread mapping (bf16 sources, no conversion in loop)
    const int kr  = tid >> 3, kcg = tid & 7;     // K: key row kr, dims kcg*16..+15
    const int lrow = ((kr & 1) << 4) | (kr >> 1);  // interleaved LDS row
    const int vd  = tid >> 1, vh = tid & 1;      // V^T: dim row vd, key half vh*16

    int kt0 = q0 - WIN; if (kt0 < 0) kt0 = 0;
    const int kend = q0 + 32;

    const int koff = lrow * KSTR + kcg * 16;   // staging write offsets (within buf)
    const int voff = vd * VSTR + vh * 16;

    uint4 kpre0, kpre1, vpre0, vpre1;
    {
        const unsigned short* kp = kbase + (size_t)(kt0 + kr) * KROW + kcg * 16;
        kpre0 = *(const uint4*)(kp);
        kpre1 = *(const uint4*)(kp + 8);
        const unsigned short* vp = vtbase + (size_t)vd * SEQ + kt0 + vh * 16;
        vpre0 = *(const uint4*)(vp);
        vpre1 = *(const uint4*)(vp + 8);
    }

    int pp = 0;
    for (int k0 = kt0; k0 < kend; k0 += 32, pp ^= 1) {
        // ---- commit staged tile into buf pp (pure b128 writes) ----
        *(uint4*)&Klds[pp][koff]     = kpre0;
        *(uint4*)&Klds[pp][koff + 8] = kpre1;
        *(uint4*)&Vlds[pp][voff]     = vpre0;
        *(uint4*)&Vlds[pp][voff + 8] = vpre1;
        __syncthreads();   // single barrier per tile (double-buffered)
        // ---- prefetch next tile: issued after the barrier, in flight
        // across the whole compute phase below ----
        if (k0 + 32 < kend) {
            const unsigned short* kp = kbase + (size_t)(k0 + 32 + kr) * KROW + kcg * 16;
            kpre0 = *(const uint4*)(kp);
            kpre1 = *(const uint4*)(kp + 8);
            const unsigned short* vp = vtbase + (size_t)vd * SEQ + (k0 + 32) + vh * 16;
            vpre0 = *(const uint4*)(vp);
            vpre1 = *(const uint4*)(vp + 8);
        }

        // ---- S^T = K * Q^T : C row = interleaved key, col = query = l15 ----
        float4v sacc[2][2]; // [ks(parity)][qs]
        sacc[0][0] = (float4v)0.0f; sacc[0][1] = (float4v)0.0f;
        sacc[1][0] = (float4v)0.0f; sacc[1][1] = (float4v)0.0f;
        __builtin_amdgcn_s_setprio(1);
#pragma unroll
        for (int c = 0; c < 4; ++c) {
            short8 kf0 = *(const short8*)&Klds[pp][(l15)      * KSTR + c * 32 + quad * 8];
            short8 kf1 = *(const short8*)&Klds[pp][(16 + l15) * KSTR + c * 32 + quad * 8];
            sacc[0][0] = __builtin_amdgcn_mfma_f32_16x16x32_bf16(kf0, qf[0][c], sacc[0][0], 0, 0, 0);
            sacc[0][1] = __builtin_amdgcn_mfma_f32_16x16x32_bf16(kf0, qf[1][c], sacc[0][1], 0, 0, 0);
            sacc[1][0] = __builtin_amdgcn_mfma_f32_16x16x32_bf16(kf1, qf[0][c], sacc[1][0], 0, 0, 0);
            sacc[1][1] = __builtin_amdgcn_mfma_f32_16x16x32_bf16(kf1, qf[1][c], sacc[1][1], 0, 0, 0);
        }
        __builtin_amdgcn_s_setprio(0);

        // ---- hoist all V fragments: lgkm latency hides under softmax VALU ----
        short8 vf[8];
#pragma unroll
        for (int f = 0; f < 8; ++f)
            vf[f] = *(const short8*)&Vlds[pp][(f * 16 + l15) * VSTR + quad * 8];

        // ---- per-qs: softmax then PV immediately (MFMA pipe busy while the
        // other qs' softmax VALU runs) ----
        // key = k0 + 8*quad + 2r + ks
#pragma unroll
        for (int qs = 0; qs < 2; ++qs) {
            const int query = q0 + qs * 16 + l15;
            const bool full = (k0 + 31 <= q0 + qs * 16) && (q0 + qs * 16 + 15 - k0 <= WIN);
            float ps[2][4];
            float mx = -3.0e38f;
            if (full) {
#pragma unroll
                for (int ks = 0; ks < 2; ++ks)
#pragma unroll
                    for (int r = 0; r < 4; ++r) {
                        float s = sacc[ks][qs][r];
                        ps[ks][r] = s;
                        mx = fmaxf(mx, s);
                    }
            } else {
#pragma unroll
                for (int ks = 0; ks < 2; ++ks)
#pragma unroll
                    for (int r = 0; r < 4; ++r) {
                        const int key = k0 + 8 * quad + 2 * r + ks;
                        const unsigned d = (unsigned)(query - key);
                        float s = (d <= WIN) ? sacc[ks][qs][r] : -1.0e30f;
                        ps[ks][r] = s;
                        mx = fmaxf(mx, s);
                    }
            }
            mx = fmaxf(mx, __shfl_xor(mx, 16));
            mx = fmaxf(mx, __shfl_xor(mx, 32));
            const float mold = m_i[qs];
            float mnew = mold;
            // defer-max: rescale only when some query's tile-max exceeds the
            // running max by more than DTHR; otherwise P <= 2^DTHR (safe).
            if (__any(mx > mold + DTHR)) {
                mnew = fmaxf(mold, mx);
                m_i[qs] = mnew;
                const float alpha = exp2f(mold - mnew);
                l_i[qs] *= alpha;
#pragma unroll
                for (int r = 0; r < 4; ++r) {
                    const float ar = __shfl(alpha, quad * 4 + r);
#pragma unroll
                    for (int f = 0; f < 8; ++f) accO[qs][f][r] *= ar;
                }
            }
            float sum = 0.0f;
            short8 pf;
            {
                union { unsigned int u[4]; short8 s; } cv;
#pragma unroll
                for (int r = 0; r < 4; ++r) {
                    const float p0 = exp2f(ps[0][r] - mnew);
                    const float p1 = exp2f(ps[1][r] - mnew);
                    sum += p0 + p1;
                    cv.u[r] = pk2bf(p0, p1);
                }
                pf = cv.s;
            }
            l_i[qs] += sum;       // per-lane partial (8 keys); reduced in epilogue

            // ---- O += P*V via 16x16x32 (B-frag = preloaded vf) ----
            __builtin_amdgcn_s_setprio(1);
#pragma unroll
            for (int f = 0; f < 8; ++f)
                accO[qs][f] = __builtin_amdgcn_mfma_f32_16x16x32_bf16(pf, vf[f], accO[qs][f], 0, 0, 0);
            __builtin_amdgcn_s_setprio(0);
        }
    }

    // ---- epilogue: reduce per-lane l_i across quads, add sink, scale, store ----
    float* obase = og + (size_t)(b * SEQ) * QROW + h * HD;
#pragma unroll
    for (int qs = 0; qs < 2; ++qs) {
        float l = l_i[qs];
        l += __shfl_xor(l, 16);
        l += __shfl_xor(l, 32);
        l += exp2f(sinkv - m_i[qs]);   // sink contribution, counted exactly once
#pragma unroll
        for (int r = 0; r < 4; ++r) {
            const float lq  = __shfl(l, quad * 4 + r);
            const float inv = __builtin_amdgcn_rcpf(lq);
            float* orow = obase + (size_t)(q0 + qs * 16 + quad * 4 + r) * QROW;
#pragma unroll
            for (int f = 0; f < 8; ++f)
                orow[f * 16 + l15] = accO[qs][f][r] * inv;
        }
    }
}

extern "C" void kernel_launch(void* const* d_in, const int* in_sizes, int n_in,
                              void* d_out, int out_size, void* d_ws, size_t ws_size,
                              hipStream_t stream) {
    const float* q     = (const float*)d_in[0];
    const float* k     = (const float*)d_in[1];
    const float* v     = (const float*)d_in[2];
    const float* sinks = (const float*)d_in[3];
    float* o = (float*)d_out;

    unsigned short* kb = (unsigned short*)d_ws;                      // 8 MB
    unsigned short* vt = kb + (size_t)NB * SEQ * KROW;               // 8 MB

    // pre-pass: K -> bf16 (4M elems / 8 per thread / 256)
    cvt_k_kernel<<<dim3(NB * SEQ * KROW / (256 * 8)), dim3(256), 0, stream>>>(k, kb);
    // pre-pass: V -> V^T bf16 tiles
    cvt_vt_kernel<<<dim3(NB * NKVH * (SEQ / 64)), dim3(256), 0, stream>>>(v, vt);

    attn_swa_sink_kernel<<<dim3(NB * NKVH * (SEQ / 32)), dim3(256), 0, stream>>>(
        q, kb, vt, sinks, o);
}

// Round 12
// 212.431 us; speedup vs baseline: 1.6794x; 1.6794x over previous
//
#include <hip/hip_runtime.h>
#include <hip/hip_bf16.h>

#define NH    16
#define NKVH  4
#define HD    128
#define WIN   1024
#define SEQ   2048
#define NB    4
#define QROW  (NH * HD)    // 2048 floats per token row (q, o)
#define KROW  (NKVH * HD)  // 512 elems per token row (k, v)
#define LOG2E 1.4426950408889634f
#define QSC   (0.08838834764831845f * LOG2E)
#define DTHR  8.0f         // defer-max threshold (log2 domain): P bounded by 2^8

#define KSTR 136   // Klds row stride in shorts (17x16B, 2-way max on A-frag reads)
#define VSTR 40    // Vlds row stride in shorts (5x16B)

typedef __attribute__((ext_vector_type(8))) short short8;
typedef __attribute__((ext_vector_type(4))) float float4v;

// bare v_exp_f32 (2^x) when available: exp2f without fast-math goes through the
// OCML denormal-guard sequence (~5 VALU); our args are bounded above by DTHR
// and masked lanes want exactly 0, so the raw op is sufficient.
#if defined(__has_builtin)
#if __has_builtin(__builtin_amdgcn_exp2f)
#define FEXP2(x) __builtin_amdgcn_exp2f(x)
#endif
#endif
#ifndef FEXP2
#define FEXP2(x) exp2f(x)
#endif

__device__ __forceinline__ unsigned short f2bf(float f) {
    unsigned int u = __float_as_uint(f);
    unsigned int r = (u + 0x7FFFu + ((u >> 16) & 1u)) >> 16;
    return (unsigned short)r;
}

__device__ __forceinline__ unsigned int pk2bf(float a, float b) {
    float2 t; t.x = a; t.y = b;
    __hip_bfloat162 h = __float22bfloat162_rn(t);
    union { __hip_bfloat162 h; unsigned int u; } cv;
    cv.h = h;
    return cv.u;
}

// ---- pre-pass 1: K fp32 -> bf16, layout preserved [token][kvh*128+d] ----
__global__ __launch_bounds__(256)
void cvt_k_kernel(const float* __restrict__ kg, unsigned short* __restrict__ kb) {
    const size_t idx = ((size_t)blockIdx.x * 256 + threadIdx.x) * 8;
    float4 a = *(const float4*)(kg + idx);
    float4 b = *(const float4*)(kg + idx + 4);
    uint4 w;
    w.x = pk2bf(a.x, a.y); w.y = pk2bf(a.z, a.w);
    w.z = pk2bf(b.x, b.y); w.w = pk2bf(b.z, b.w);
    *(uint4*)(kb + idx) = w;
}

// ---- pre-pass 2: V fp32 [token][kvh*128+d] -> V^T bf16 [b][kvh][d][seq] ----
#define VTSTR 72
__global__ __launch_bounds__(256)
void cvt_vt_kernel(const float* __restrict__ vg, unsigned short* __restrict__ vt) {
    __shared__ unsigned short T[128 * VTSTR];
    const int blk = blockIdx.x;          // 512 = b(4) x kvh(4) x kb(32)
    const int b   = blk >> 7;
    const int kvh = (blk >> 5) & 3;
    const int kb  = blk & 31;
    const int t   = threadIdx.x;

    // read: 64 keys x 128 dims fp32, coalesced; scatter-transpose into LDS
    const int klocal = t >> 2;
    const int d0     = (t & 3) * 32;
    const float* src = vg + (size_t)(b * SEQ + kb * 64 + klocal) * KROW + kvh * HD + d0;
#pragma unroll
    for (int c = 0; c < 8; ++c) {
        float4 x = *(const float4*)(src + c * 4);
        T[(d0 + c * 4 + 0) * VTSTR + klocal] = f2bf(x.x);
        T[(d0 + c * 4 + 1) * VTSTR + klocal] = f2bf(x.y);
        T[(d0 + c * 4 + 2) * VTSTR + klocal] = f2bf(x.z);
        T[(d0 + c * 4 + 3) * VTSTR + klocal] = f2bf(x.w);
    }
    __syncthreads();

    // write: dim-major rows, 64B per thread contiguous
    const int d    = t >> 1;
    const int half = t & 1;
    const unsigned short* s = &T[d * VTSTR + half * 32];
    unsigned short* dst = vt + ((size_t)((b * NKVH + kvh) * HD) + d) * SEQ + kb * 64 + half * 32;
#pragma unroll
    for (int c = 0; c < 4; ++c)
        *(uint4*)(dst + c * 8) = *(const uint4*)(s + c * 8);
}

// block = 256 threads = 4 waves; wave w = head kvh*4+w, 32 queries (qs=0..1).
// Round-6 verified structure: double-buffered LDS, ONE barrier per tile,
// prefetch issued after the barrier (in flight across the compute phase),
// defer-max, per-lane partial l_i (sink added once in epilogue), (256,3)
// (caps below ~170 VGPR spill catastrophically - rounds 4/7; added live
// arrays get demoted to scratch - round 11).
// Round-12 deltas (dead-cost removal only, no structural change):
//  - exp2f -> bare v_exp_f32 via guarded __builtin_amdgcn_exp2f
//  - staging pointers advanced by constants (no per-tile 64-bit recompute)
//  - balanced fmax tree for the tile max (shorter dependency chain)
__global__ __launch_bounds__(256, 3)
void attn_swa_sink_kernel(const float* __restrict__ qg,
                          const unsigned short* __restrict__ kb,
                          const unsigned short* __restrict__ vt,
                          const float* __restrict__ sinks,
                          float* __restrict__ og) {
    __shared__ __align__(16) unsigned short Klds[2][32 * KSTR];   // [buf][interleaved key][dim]
    __shared__ __align__(16) unsigned short Vlds[2][128 * VSTR];  // [buf][dim][key] (V^T)

    // XCD swizzle: q-tiles of one (b,kvh) stay on one XCD; longest tiles first.
    const int gid  = blockIdx.x;          // 1024 = 8 xcd x 2 gsel x 64 qt
    const int xcd  = gid & 7;
    const int rest = gid >> 3;
    const int qt   = 63 - (rest >> 1);
    const int g    = ((rest & 1) << 3) | xcd;
    const int b    = g >> 2;
    const int kvh  = g & 3;

    const int tid  = threadIdx.x;
    const int wave = tid >> 6;
    const int lane = tid & 63;
    const int l15  = lane & 15;
    const int quad = lane >> 4;
    const int h    = kvh * 4 + wave;
    const int q0   = qt * 32;

    const float* qbase = qg + (size_t)(b * SEQ) * QROW;
    const unsigned short* kbase = kb + (size_t)(b * SEQ) * KROW + kvh * HD;
    const unsigned short* vtbase = vt + (size_t)((b * NKVH + kvh) * HD) * SEQ;

    // ---- Q fragments (B-operand of K*Q^T): col=query=l15, k=dim=quad*8+j (+32c) ----
    short8 qf[2][4];
#pragma unroll
    for (int qs = 0; qs < 2; ++qs) {
        const float* qr = qbase + (size_t)(q0 + qs * 16 + l15) * QROW + h * HD + quad * 8;
#pragma unroll
        for (int c = 0; c < 4; ++c) {
            float4 x = *(const float4*)(qr + c * 32);
            float4 y = *(const float4*)(qr + c * 32 + 4);
            union { unsigned int u[4]; short8 s; } cv;
            cv.u[0] = pk2bf(x.x * QSC, x.y * QSC);
            cv.u[1] = pk2bf(x.z * QSC, x.w * QSC);
            cv.u[2] = pk2bf(y.x * QSC, y.y * QSC);
            cv.u[3] = pk2bf(y.z * QSC, y.w * QSC);
            qf[qs][c] = cv.s;
        }
    }

    const float sinkv = sinks[h] * LOG2E;
    float m_i[2] = { sinkv, sinkv };
    float l_i[2] = { 0.0f, 0.0f };   // per-lane partial; sink added in epilogue
    float4v accO[2][8];   // row=query=quad*4+r, col=dim=f*16+l15
#pragma unroll
    for (int qs = 0; qs < 2; ++qs)
#pragma unroll
        for (int f = 0; f < 8; ++f) accO[qs][f] = (float4v)0.0f;

    // staging thread mapping (bf16 sources, no conversion in loop)
    const int kr  = tid >> 3, kcg = tid & 7;     // K: key row kr, dims kcg*16..+15
    const int lrow = ((kr & 1) << 4) | (kr >> 1);  // interleaved LDS row
    const int vd  = tid >> 1, vh = tid & 1;      // V^T: dim row vd, key half vh*16

    int kt0 = q0 - WIN; if (kt0 < 0) kt0 = 0;
    const int kend = q0 + 32;

    const int koff = lrow * KSTR + kcg * 16;   // staging write offsets (within buf)
    const int voff = vd * VSTR + vh * 16;

    // persistent staging pointers, advanced by compile-time constants
    const unsigned short* kpsrc = kbase + (size_t)(kt0 + kr) * KROW + kcg * 16;
    const unsigned short* vpsrc = vtbase + (size_t)vd * SEQ + kt0 + vh * 16;

    uint4 kpre0, kpre1, vpre0, vpre1;
    kpre0 = *(const uint4*)(kpsrc);
    kpre1 = *(const uint4*)(kpsrc + 8);
    vpre0 = *(const uint4*)(vpsrc);
    vpre1 = *(const uint4*)(vpsrc + 8);
    kpsrc += (size_t)32 * KROW;
    vpsrc += 32;

    int pp = 0;
    for (int k0 = kt0; k0 < kend; k0 += 32, pp ^= 1) {
        // ---- commit staged tile into buf pp (pure b128 writes) ----
        *(uint4*)&Klds[pp][koff]     = kpre0;
        *(uint4*)&Klds[pp][koff + 8] = kpre1;
        *(uint4*)&Vlds[pp][voff]     = vpre0;
        *(uint4*)&Vlds[pp][voff + 8] = vpre1;
        __syncthreads();   // single barrier per tile (double-buffered)
        // ---- prefetch next tile: issued after the barrier, in flight
        // across the whole compute phase below ----
        if (k0 + 32 < kend) {
            kpre0 = *(const uint4*)(kpsrc);
            kpre1 = *(const uint4*)(kpsrc + 8);
            vpre0 = *(const uint4*)(vpsrc);
            vpre1 = *(const uint4*)(vpsrc + 8);
            kpsrc += (size_t)32 * KROW;
            vpsrc += 32;
        }

        // ---- S^T = K * Q^T : C row = interleaved key, col = query = l15 ----
        float4v sacc[2][2]; // [ks(parity)][qs]
        sacc[0][0] = (float4v)0.0f; sacc[0][1] = (float4v)0.0f;
        sacc[1][0] = (float4v)0.0f; sacc[1][1] = (float4v)0.0f;
        __builtin_amdgcn_s_setprio(1);
#pragma unroll
        for (int c = 0; c < 4; ++c) {
            short8 kf0 = *(const short8*)&Klds[pp][(l15)      * KSTR + c * 32 + quad * 8];
            short8 kf1 = *(const short8*)&Klds[pp][(16 + l15) * KSTR + c * 32 + quad * 8];
            sacc[0][0] = __builtin_amdgcn_mfma_f32_16x16x32_bf16(kf0, qf[0][c], sacc[0][0], 0, 0, 0);
            sacc[0][1] = __builtin_amdgcn_mfma_f32_16x16x32_bf16(kf0, qf[1][c], sacc[0][1], 0, 0, 0);
            sacc[1][0] = __builtin_amdgcn_mfma_f32_16x16x32_bf16(kf1, qf[0][c], sacc[1][0], 0, 0, 0);
            sacc[1][1] = __builtin_amdgcn_mfma_f32_16x16x32_bf16(kf1, qf[1][c], sacc[1][1], 0, 0, 0);
        }
        __builtin_amdgcn_s_setprio(0);

        // ---- online softmax (defer-max); P packs into x32 A-layout ----
        // key = k0 + 8*quad + 2r + ks
        short8 pf[2];
#pragma unroll
        for (int qs = 0; qs < 2; ++qs) {
            const int query = q0 + qs * 16 + l15;
            const bool full = (k0 + 31 <= q0 + qs * 16) && (q0 + qs * 16 + 15 - k0 <= WIN);
            float4v s0 = sacc[0][qs], s1 = sacc[1][qs];
            if (!full) {
#pragma unroll
                for (int r = 0; r < 4; ++r) {
                    const int key0 = k0 + 8 * quad + 2 * r;
                    if ((unsigned)(query - key0) > WIN)     s0[r] = -1.0e30f;
                    if ((unsigned)(query - key0 - 1) > WIN) s1[r] = -1.0e30f;
                }
            }
            // balanced tree (max3-fusable) instead of the 8-deep serial chain
            float mx = fmaxf(fmaxf(fmaxf(s0[0], s1[0]), fmaxf(s0[1], s1[1])),
                             fmaxf(fmaxf(s0[2], s1[2]), fmaxf(s0[3], s1[3])));
            mx = fmaxf(mx, __shfl_xor(mx, 16));
            mx = fmaxf(mx, __shfl_xor(mx, 32));
            const float mold = m_i[qs];
            float mnew = mold;
            // defer-max: rescale only when some query's tile-max exceeds the
            // running max by more than DTHR; otherwise P <= 2^DTHR (safe).
            if (__any(mx > mold + DTHR)) {
                mnew = fmaxf(mold, mx);
                m_i[qs] = mnew;
                const float alpha = FEXP2(mold - mnew);
                l_i[qs] *= alpha;
#pragma unroll
                for (int r = 0; r < 4; ++r) {
                    const float ar = __shfl(alpha, quad * 4 + r);
#pragma unroll
                    for (int f = 0; f < 8; ++f) accO[qs][f][r] *= ar;
                }
            }
            float sum = 0.0f;
            union { unsigned int u[4]; short8 s; } cv;
#pragma unroll
            for (int r = 0; r < 4; ++r) {
                const float p0 = FEXP2(s0[r] - mnew);
                const float p1 = FEXP2(s1[r] - mnew);
                sum += p0 + p1;
                cv.u[r] = pk2bf(p0, p1);
            }
            l_i[qs] += sum;       // per-lane partial (8 keys); reduced in epilogue
            pf[qs] = cv.s;
        }

        // ---- O += P*V via 16x16x32 (B-frag = contiguous b128 from V^T) ----
        __builtin_amdgcn_s_setprio(1);
#pragma unroll
        for (int f = 0; f < 8; ++f) {
            short8 vf = *(const short8*)&Vlds[pp][(f * 16 + l15) * VSTR + quad * 8];
            accO[0][f] = __builtin_amdgcn_mfma_f32_16x16x32_bf16(pf[0], vf, accO[0][f], 0, 0, 0);
            accO[1][f] = __builtin_amdgcn_mfma_f32_16x16x32_bf16(pf[1], vf, accO[1][f], 0, 0, 0);
        }
        __builtin_amdgcn_s_setprio(0);
    }

    // ---- epilogue: reduce per-lane l_i across quads, add sink, scale, store ----
    float* obase = og + (size_t)(b * SEQ) * QROW + h * HD;
#pragma unroll
    for (int qs = 0; qs < 2; ++qs) {
        float l = l_i[qs];
        l += __shfl_xor(l, 16);
        l += __shfl_xor(l, 32);
        l += FEXP2(sinkv - m_i[qs]);   // sink contribution, counted exactly once
#pragma unroll
        for (int r = 0; r < 4; ++r) {
            const float lq  = __shfl(l, quad * 4 + r);
            const float inv = __builtin_amdgcn_rcpf(lq);
            float* orow = obase + (size_t)(q0 + qs * 16 + quad * 4 + r) * QROW;
#pragma unroll
            for (int f = 0; f < 8; ++f)
                orow[f * 16 + l15] = accO[qs][f][r] * inv;
        }
    }
}

extern "C" void kernel_launch(void* const* d_in, const int* in_sizes, int n_in,
                              void* d_out, int out_size, void* d_ws, size_t ws_size,
                              hipStream_t stream) {
    const float* q     = (const float*)d_in[0];
    const float* k     = (const float*)d_in[1];
    const float* v     = (const float*)d_in[2];
    const float* sinks = (const float*)d_in[3];
    float* o = (float*)d_out;

    unsigned short* kb = (unsigned short*)d_ws;                      // 8 MB
    unsigned short* vt = kb + (size_t)NB * SEQ * KROW;               // 8 MB

    // pre-pass: K -> bf16 (4M elems / 8 per thread / 256)
    cvt_k_kernel<<<dim3(NB * SEQ * KROW / (256 * 8)), dim3(256), 0, stream>>>(k, kb);
    // pre-pass: V -> V^T bf16 tiles
    cvt_vt_kernel<<<dim3(NB * NKVH * (SEQ / 64)), dim3(256), 0, stream>>>(v, vt);

    attn_swa_sink_kernel<<<dim3(NB * NKVH * (SEQ / 32)), dim3(256), 0, stream>>>(
        q, kb, vt, sinks, o);
}